// Round 2
// baseline (351.575 us; speedup 1.0000x reference)
//
#include <hip/hip_runtime.h>

#define NHEADS 16
#define NW 8
#define SEQ 1024
#define BATCH 8
#define EMB 128
#define KSPLIT 4
#define KC 256          // keys per block (SEQ / KSPLIT)
#define PW 132          // Wl LDS row pad (floats)
#define PP 132          // Pl LDS row pad (floats)

// quantum_heads closed form for one (b,s,head) row (fp32 input):
// c[w] = cos(x[w] + theta[w]); z[0] = c1..c7; z[w>=1] = c0..cw
__device__ __forceinline__ void qrow(const float* __restrict__ xp,
                                     const float* __restrict__ th, float* z) {
    float4 a = *reinterpret_cast<const float4*>(xp);
    float4 b = *reinterpret_cast<const float4*>(xp + 4);
    float c0 = __cosf(a.x + th[0]);
    float c1 = __cosf(a.y + th[1]);
    float c2 = __cosf(a.z + th[2]);
    float c3 = __cosf(a.w + th[3]);
    float c4 = __cosf(b.x + th[4]);
    float c5 = __cosf(b.y + th[5]);
    float c6 = __cosf(b.z + th[6]);
    float c7 = __cosf(b.w + th[7]);
    // z0 = c1*...*c7 computed directly (no divide -> no 0/0 risk)
    float u = c1 * c2;
    u *= c3; u *= c4; u *= c5; u *= c6; u *= c7;
    z[0] = u;
    z[1] = c0 * c1;
    z[2] = z[1] * c2;
    z[3] = z[2] * c3;
    z[4] = z[3] * c4;
    z[5] = z[4] * c5;
    z[6] = z[5] * c6;
    z[7] = z[6] * c7;
}

// Kernel A: partial attention. Grid = B*H*KSPLIT. Block = 256.
// Each block: one (b,h), one 256-key chunk in LDS; each thread: 4 queries.
// No-max softmax (|score| <= 2.83) -> partials are plain sums -> atomicAdd.
__global__ __launch_bounds__(256, 2) void qattn_partial(
    const float* __restrict__ x,
    const float* __restrict__ theta,
    float* __restrict__ o_ws,   // [B*S, 16, 8] fp32
    float* __restrict__ l_ws)   // [B*S, 16]   fp32
{
    __shared__ float kv[KC * NW];
    const int t  = threadIdx.x;
    const int bh = blockIdx.x >> 2;
    const int kc = blockIdx.x & 3;
    const int b  = bh >> 4, h = bh & 15;

    float th[8];
#pragma unroll
    for (int w = 0; w < 8; ++w) th[w] = theta[w];   // wave-uniform -> s_loads

    // stage 1: build key slab (keys kc*256 .. +255), one row per thread
    {
        const int sk = kc * KC + t;
        const float* xp = x + ((size_t)(b * SEQ + sk) * EMB + h * NW);
        float z[8];
        qrow(xp, th, z);
#pragma unroll
        for (int d = 0; d < 8; ++d) kv[t * 8 + d] = z[d];
    }
    __syncthreads();

    // stage 2: 4 queries per thread (q = t, t+256, t+512, t+768)
    const float SCALE = 0.35355339059327373f;  // 1/sqrt(8), folded into q
    float qv[4][8], oacc[4][8], lac[4];
#pragma unroll
    for (int i = 0; i < 4; ++i) {
        const int q = i * 256 + t;
        const float* xp = x + ((size_t)(b * SEQ + q) * EMB + h * NW);
        float z[8];
        qrow(xp, th, z);
#pragma unroll
        for (int d = 0; d < 8; ++d) { qv[i][d] = z[d] * SCALE; oacc[i][d] = 0.f; }
        lac[i] = 0.f;
    }

    const float4* kv4 = reinterpret_cast<const float4*>(kv);
    for (int k = 0; k < KC; ++k) {
        float4 ka = kv4[2 * k];      // all lanes same address -> LDS broadcast
        float4 kb = kv4[2 * k + 1];
#pragma unroll
        for (int i = 0; i < 4; ++i) {
            float s = qv[i][0] * ka.x + qv[i][1] * ka.y + qv[i][2] * ka.z + qv[i][3] * ka.w
                    + qv[i][4] * kb.x + qv[i][5] * kb.y + qv[i][6] * kb.z + qv[i][7] * kb.w;
            float p = __expf(s);
            lac[i] += p;
            oacc[i][0] += p * ka.x; oacc[i][1] += p * ka.y;
            oacc[i][2] += p * ka.z; oacc[i][3] += p * ka.w;
            oacc[i][4] += p * kb.x; oacc[i][5] += p * kb.y;
            oacc[i][6] += p * kb.z; oacc[i][7] += p * kb.w;
        }
    }

#pragma unroll
    for (int i = 0; i < 4; ++i) {
        const int q   = i * 256 + t;
        const int row = b * SEQ + q;
        float* op = o_ws + ((size_t)row * 16 + h) * 8;
#pragma unroll
        for (int d = 0; d < 8; ++d) atomicAdd(op + d, oacc[i][d]);
        atomicAdd(l_ws + (size_t)row * 16 + h, lac[i]);
    }
}

// Kernel B: out[row, e] = sum_f (o[row,f]/l[row,f/8]) * W[e,f] + bias[e].
// Grid = 8192/32 blocks, 256 threads, 32 rows/block. W + proj in LDS,
// padded strides -> <=4-way conflicts. 4x4 register tile per thread.
__global__ __launch_bounds__(256) void proj_out(
    const float* __restrict__ o_ws,
    const float* __restrict__ l_ws,
    const float* __restrict__ W,
    const float* __restrict__ bias,
    float* __restrict__ out)
{
    __shared__ float Wl[EMB * PW];            // 67.6 KB
    __shared__ float Pl[32 * PP];             // 16.9 KB
    __shared__ float linv[32 * 16];
    const int t    = threadIdx.x;
    const int row0 = blockIdx.x * 32;

    // 1/l for the block's 32 rows x 16 heads
#pragma unroll
    for (int i = 0; i < 2; ++i) {
        const int g = t + 256 * i;              // 512 values, contiguous
        linv[g] = 1.0f / l_ws[(size_t)row0 * 16 + g];
    }
    __syncthreads();

    // W -> LDS (row-major, padded), float4 chunks, coalesced
#pragma unroll
    for (int i = 0; i < 16; ++i) {
        const int g = t + 256 * i;              // 4096 float4 groups
        const int e = g >> 5;
        const int f = (g & 31) * 4;
        float4 u = *reinterpret_cast<const float4*>(W + (size_t)g * 4);
        *reinterpret_cast<float4*>(&Wl[e * PW + f]) = u;
    }
    // proj = o / l -> LDS
#pragma unroll
    for (int i = 0; i < 4; ++i) {
        const int g  = t + 256 * i;             // 1024 float4 groups
        const int r  = g >> 5;
        const int k0 = (g & 31) * 4;
        float4 v = *reinterpret_cast<const float4*>(o_ws + (size_t)(row0 + r) * EMB + k0);
        const float s = linv[r * 16 + (k0 >> 3)];
        v.x *= s; v.y *= s; v.z *= s; v.w *= s;
        *reinterpret_cast<float4*>(&Pl[r * PP + k0]) = v;
    }
    __syncthreads();

    const int rt = t & 7,  ct = t >> 3;
    const int r0 = rt * 4, c0 = ct * 4;
    float acc[4][4];
#pragma unroll
    for (int ri = 0; ri < 4; ++ri)
#pragma unroll
        for (int j = 0; j < 4; ++j) acc[ri][j] = 0.f;

    for (int kk = 0; kk < EMB; kk += 4) {
        float4 a[4];
#pragma unroll
        for (int j = 0; j < 4; ++j)
            a[j] = *reinterpret_cast<const float4*>(&Pl[(r0 + j) * PP + kk]);
        float4 w[4];
#pragma unroll
        for (int j = 0; j < 4; ++j)
            w[j] = *reinterpret_cast<const float4*>(&Wl[(c0 + j) * PW + kk]);
#pragma unroll
        for (int ri = 0; ri < 4; ++ri) {
#pragma unroll
            for (int j = 0; j < 4; ++j)
                acc[ri][j] += a[ri].x * w[j].x + a[ri].y * w[j].y
                            + a[ri].z * w[j].z + a[ri].w * w[j].w;
        }
    }

    float bv[4];
#pragma unroll
    for (int j = 0; j < 4; ++j) bv[j] = bias[c0 + j];
#pragma unroll
    for (int ri = 0; ri < 4; ++ri) {
        const int row = row0 + r0 + ri;
        float4 o;
        o.x = acc[ri][0] + bv[0];
        o.y = acc[ri][1] + bv[1];
        o.z = acc[ri][2] + bv[2];
        o.w = acc[ri][3] + bv[3];
        *reinterpret_cast<float4*>(out + (size_t)row * EMB + c0) = o;
    }
}

extern "C" void kernel_launch(void* const* d_in, const int* in_sizes, int n_in,
                              void* d_out, int out_size, void* d_ws, size_t ws_size,
                              hipStream_t stream)
{
    const float* x     = (const float*)d_in[0];
    const float* theta = (const float*)d_in[1];
    const float* W     = (const float*)d_in[2];
    const float* bias  = (const float*)d_in[3];
    float* out = (float*)d_out;

    const size_t ROWS = (size_t)BATCH * SEQ;          // 8192
    float* o_ws = (float*)d_ws;                       // ROWS*128 fp32 = 4 MB
    float* l_ws = (float*)((char*)d_ws + ROWS * EMB * sizeof(float));
    const size_t zero_bytes = ROWS * EMB * sizeof(float) + ROWS * NHEADS * sizeof(float);

    hipMemsetAsync(d_ws, 0, zero_bytes, stream);
    qattn_partial<<<BATCH * NHEADS * KSPLIT, 256, 0, stream>>>(x, theta, o_ws, l_ws);
    proj_out<<<(int)(ROWS / 32), 256, 0, stream>>>(o_ws, l_ws, W, bias, out);
}

// Round 3
// 161.593 us; speedup vs baseline: 2.1757x; 2.1757x over previous
//
#include <hip/hip_runtime.h>

#define NHEADS 16
#define NW 8
#define SEQ 1024
#define BATCH 8
#define EMB 128
#define KSPLIT 2
#define QSPLIT 4
#define KC (SEQ / KSPLIT)      // 512 keys per block
#define QC (SEQ / QSPLIT)      // 256 queries per block (1/thread)
#define PW 132                 // proj LDS row pad (floats)

// quantum_heads closed form for one (b,s,head) row (fp32 input):
// c[w] = cos(x[w] + theta[w]); z[0] = c1..c7; z[w>=1] = c0..cw
__device__ __forceinline__ void qrow(const float* __restrict__ xp,
                                     const float* __restrict__ th, float* z) {
    float4 a = *reinterpret_cast<const float4*>(xp);
    float4 b = *reinterpret_cast<const float4*>(xp + 4);
    float c0 = __cosf(a.x + th[0]);
    float c1 = __cosf(a.y + th[1]);
    float c2 = __cosf(a.z + th[2]);
    float c3 = __cosf(a.w + th[3]);
    float c4 = __cosf(b.x + th[4]);
    float c5 = __cosf(b.y + th[5]);
    float c6 = __cosf(b.z + th[6]);
    float c7 = __cosf(b.w + th[7]);
    float u = c1 * c2;
    u *= c3; u *= c4; u *= c5; u *= c6; u *= c7;
    z[0] = u;
    z[1] = c0 * c1;
    z[2] = z[1] * c2;
    z[3] = z[2] * c3;
    z[4] = z[3] * c4;
    z[5] = z[4] * c5;
    z[6] = z[5] * c6;
    z[7] = z[6] * c7;
}

// Kernel A: partial attention, atomic-free split-K.
// grid = 128 bh * QSPLIT * KSPLIT = 1024 blocks, 256 threads, 1 query/thread.
// Keys for the block's chunk staged in LDS (16KB); partials to o_part/l_part.
__global__ __launch_bounds__(256, 4) void qattn_partial(
    const float* __restrict__ x,
    const float* __restrict__ theta,
    float* __restrict__ o_part,   // [KSPLIT][128 bh][1024 s][8] fp32
    float* __restrict__ l_part)   // [KSPLIT][128 bh][1024 s]    fp32
{
    __shared__ float kv[KC * NW];           // 16 KB
    const int t   = threadIdx.x;
    const int idx = blockIdx.x;
    const int kc  = idx & (KSPLIT - 1);
    const int qc  = (idx >> 1) & (QSPLIT - 1);
    const int bh  = idx >> 3;               // 0..127
    const int b   = bh >> 4, h = bh & 15;

    float th[8];
#pragma unroll
    for (int w = 0; w < 8; ++w) th[w] = theta[w];   // wave-uniform -> s_loads

    // stage keys: 512 keys, 2 per thread
#pragma unroll
    for (int i = 0; i < 2; ++i) {
        const int kl = t + 256 * i;
        const int sk = kc * KC + kl;
        const float* xp = x + ((size_t)(b * SEQ + sk) * EMB + h * NW);
        float z[8];
        qrow(xp, th, z);
#pragma unroll
        for (int d = 0; d < 8; ++d) kv[kl * 8 + d] = z[d];
    }

    // this thread's query; fold 1/sqrt(8)*log2(e) into q so p = exp2(s) == exp(score)
    const float QS = 0.35355339059327373f * 1.4426950408889634f;
    const int  sq = qc * QC + t;
    float qv[8], oacc[8];
    {
        const float* xp = x + ((size_t)(b * SEQ + sq) * EMB + h * NW);
        float z[8];
        qrow(xp, th, z);
#pragma unroll
        for (int d = 0; d < 8; ++d) { qv[d] = z[d] * QS; oacc[d] = 0.f; }
    }
    float lac = 0.f;

    __syncthreads();

    const float4* kv4 = reinterpret_cast<const float4*>(kv);
#pragma unroll 4
    for (int k = 0; k < KC; ++k) {
        float4 ka = kv4[2 * k];      // all lanes same address -> LDS broadcast
        float4 kb = kv4[2 * k + 1];
        float s = qv[0] * ka.x + qv[1] * ka.y + qv[2] * ka.z + qv[3] * ka.w
                + qv[4] * kb.x + qv[5] * kb.y + qv[6] * kb.z + qv[7] * kb.w;
        float p = exp2f(s);          // native v_exp_f32
        lac += p;
        oacc[0] += p * ka.x; oacc[1] += p * ka.y;
        oacc[2] += p * ka.z; oacc[3] += p * ka.w;
        oacc[4] += p * kb.x; oacc[5] += p * kb.y;
        oacc[6] += p * kb.z; oacc[7] += p * kb.w;
    }

    // plain coalesced stores of this chunk's partials
    float* op = o_part + (((size_t)kc * 128 + bh) * SEQ + sq) * 8;
    *reinterpret_cast<float4*>(op)     = make_float4(oacc[0], oacc[1], oacc[2], oacc[3]);
    *reinterpret_cast<float4*>(op + 4) = make_float4(oacc[4], oacc[5], oacc[6], oacc[7]);
    l_part[((size_t)kc * 128 + bh) * SEQ + sq] = lac;
}

// Kernel B: out[row, e] = sum_f P[row,f] * W[e,f] + bias[e],
// where P[row, h*8+d] = (sum_c o_part[c])/ (sum_c l_part[c]).
// grid = (8192/32 row chunks) x (128/32 col tiles) = 1024 blocks, 256 threads.
// LDS ~35KB -> 4 blocks/CU. 2x2 register tile per thread.
__global__ __launch_bounds__(256, 4) void proj_out(
    const float* __restrict__ o_part,
    const float* __restrict__ l_part,
    const float* __restrict__ W,
    const float* __restrict__ bias,
    float* __restrict__ out)
{
    __shared__ float Pl[32 * PW];             // 16.9 KB
    __shared__ float Wl[32 * PW];             // 16.9 KB
    __shared__ float linv[32 * 16];           // 2 KB
    const int t     = threadIdx.x;
    const int row0  = blockIdx.x * 32;        // global row chunk (same b: 32 | 1024)
    const int ecol0 = blockIdx.y * 32;        // output column tile
    const int b     = row0 >> 10;
    const int s0    = row0 & 1023;

    // phase 1: 1/l for 32 rows x 16 heads
#pragma unroll
    for (int i = 0; i < 2; ++i) {
        const int g = t + 256 * i;            // 512
        const int r = g >> 4, h = g & 15;
        const size_t a = ((size_t)(b * 16 + h) * SEQ + s0 + r);
        linv[r * 16 + h] = 1.0f / (l_part[a] + l_part[128 * SEQ + a]);
    }
    __syncthreads();

    // phase 2a: stage P (sum partials, normalize). Per head: 256 contiguous floats.
#pragma unroll
    for (int i = 0; i < 4; ++i) {
        const int g  = t + 256 * i;           // 1024 float4 groups
        const int h  = g >> 6;
        const int q4 = g & 63;
        const size_t base = ((size_t)(b * 16 + h) * SEQ + s0) * 8 + q4 * 4;
        float4 v0 = *reinterpret_cast<const float4*>(o_part + base);
        float4 v1 = *reinterpret_cast<const float4*>(o_part + (size_t)128 * SEQ * 8 + base);
        const int r  = q4 >> 1;
        const int d0 = (q4 & 1) * 4;
        const float sc = linv[r * 16 + h];
        float4 v;
        v.x = (v0.x + v1.x) * sc; v.y = (v0.y + v1.y) * sc;
        v.z = (v0.z + v1.z) * sc; v.w = (v0.w + v1.w) * sc;
        *reinterpret_cast<float4*>(&Pl[r * PW + h * 8 + d0]) = v;
    }
    // phase 2b: stage W rows ecol0..ecol0+31 (coalesced)
#pragma unroll
    for (int i = 0; i < 4; ++i) {
        const int g  = t + 256 * i;           // 1024 float4 groups
        const int e  = g >> 5;
        const int k0 = (g & 31) * 4;
        *reinterpret_cast<float4*>(&Wl[e * PW + k0]) =
            *reinterpret_cast<const float4*>(W + (size_t)(ecol0 + e) * EMB + k0);
    }
    __syncthreads();

    // compute: thread -> rows r0..r0+1, cols e0..e0+1 (within tile)
    const int r0 = (t >> 4) * 2;
    const int e0 = (t & 15) * 2;
    float acc00 = 0.f, acc01 = 0.f, acc10 = 0.f, acc11 = 0.f;
    for (int kk = 0; kk < EMB; kk += 4) {
        float4 a0 = *reinterpret_cast<const float4*>(&Pl[r0 * PW + kk]);
        float4 a1 = *reinterpret_cast<const float4*>(&Pl[(r0 + 1) * PW + kk]);
        float4 w0 = *reinterpret_cast<const float4*>(&Wl[e0 * PW + kk]);
        float4 w1 = *reinterpret_cast<const float4*>(&Wl[(e0 + 1) * PW + kk]);
        acc00 += a0.x * w0.x + a0.y * w0.y + a0.z * w0.z + a0.w * w0.w;
        acc01 += a0.x * w1.x + a0.y * w1.y + a0.z * w1.z + a0.w * w1.w;
        acc10 += a1.x * w0.x + a1.y * w0.y + a1.z * w0.z + a1.w * w0.w;
        acc11 += a1.x * w1.x + a1.y * w1.y + a1.z * w1.z + a1.w * w1.w;
    }

    const float b0 = bias[ecol0 + e0], b1 = bias[ecol0 + e0 + 1];
    float2 o0 = make_float2(acc00 + b0, acc01 + b1);
    float2 o1 = make_float2(acc10 + b0, acc11 + b1);
    *reinterpret_cast<float2*>(out + (size_t)(row0 + r0) * EMB + ecol0 + e0) = o0;
    *reinterpret_cast<float2*>(out + (size_t)(row0 + r0 + 1) * EMB + ecol0 + e0) = o1;
}

extern "C" void kernel_launch(void* const* d_in, const int* in_sizes, int n_in,
                              void* d_out, int out_size, void* d_ws, size_t ws_size,
                              hipStream_t stream)
{
    const float* x     = (const float*)d_in[0];
    const float* theta = (const float*)d_in[1];
    const float* W     = (const float*)d_in[2];
    const float* bias  = (const float*)d_in[3];
    float* out = (float*)d_out;

    // workspace: o_part = KSPLIT * 128 * 1024 * 8 fp32 (8 MB), l_part = KSPLIT * 128 * 1024 (1 MB)
    float* o_part = (float*)d_ws;
    float* l_part = (float*)((char*)d_ws + (size_t)KSPLIT * 128 * SEQ * 8 * sizeof(float));

    qattn_partial<<<128 * QSPLIT * KSPLIT, 256, 0, stream>>>(x, theta, o_part, l_part);
    proj_out<<<dim3(BATCH * SEQ / 32, EMB / 32), 256, 0, stream>>>(o_part, l_part, W, bias, out);
}

// Round 4
// 131.888 us; speedup vs baseline: 2.6657x; 1.2252x over previous
//
#include <hip/hip_runtime.h>

#define NHEADS 16
#define NW 8
#define SEQ 1024
#define BATCH 8
#define EMB 128
#define KSPLIT 2
#define QSPLIT 4
#define KC (SEQ / KSPLIT)      // 512 keys per block
#define QC (SEQ / QSPLIT)      // 256 queries per block (1/thread)
#define PW 132                 // proj LDS row pad (floats)

// quantum_heads closed form for one (b,s,head) row (fp32 input):
// c[w] = cos(x[w] + theta[w]); z[0] = c1..c7; z[w>=1] = c0..cw
__device__ __forceinline__ void qrow(const float* __restrict__ xp,
                                     const float* __restrict__ th, float* z) {
    float4 a = *reinterpret_cast<const float4*>(xp);
    float4 b = *reinterpret_cast<const float4*>(xp + 4);
    float c0 = __cosf(a.x + th[0]);
    float c1 = __cosf(a.y + th[1]);
    float c2 = __cosf(a.z + th[2]);
    float c3 = __cosf(a.w + th[3]);
    float c4 = __cosf(b.x + th[4]);
    float c5 = __cosf(b.y + th[5]);
    float c6 = __cosf(b.z + th[6]);
    float c7 = __cosf(b.w + th[7]);
    float u = c1 * c2;
    u *= c3; u *= c4; u *= c5; u *= c6; u *= c7;
    z[0] = u;
    z[1] = c0 * c1;
    z[2] = z[1] * c2;
    z[3] = z[2] * c3;
    z[4] = z[3] * c4;
    z[5] = z[4] * c5;
    z[6] = z[5] * c6;
    z[7] = z[6] * c7;
}

// Kernel A: partial attention, atomic-free split-K.
// grid = 128 bh * QSPLIT * KSPLIT = 1024 blocks, 256 threads, 1 query/thread.
// kv stored as two planes [2][KC][4] so staging float4 stores are contiguous
// (conflict-free) and loop reads are uniform-address broadcasts.
__global__ __launch_bounds__(256, 4) void qattn_partial(
    const float* __restrict__ x,
    const float* __restrict__ theta,
    float* __restrict__ o_part,   // [KSPLIT][128 bh][1024 s][8] fp32
    float* __restrict__ l_part)   // [KSPLIT][128 bh][1024 s]    fp32
{
    __shared__ float kv[2 * KC * 4];        // 16 KB
    const int t   = threadIdx.x;
    const int idx = blockIdx.x;
    const int kc  = idx & (KSPLIT - 1);
    const int qc  = (idx >> 1) & (QSPLIT - 1);
    const int bh  = idx >> 3;               // 0..127
    const int b   = bh >> 4, h = bh & 15;

    float th[8];
#pragma unroll
    for (int w = 0; w < 8; ++w) th[w] = theta[w];   // wave-uniform -> s_loads

    // stage keys: 512 keys, 2 per thread; two contiguous float4 planes
#pragma unroll
    for (int i = 0; i < 2; ++i) {
        const int kl = t + 256 * i;
        const int sk = kc * KC + kl;
        const float* xp = x + ((size_t)(b * SEQ + sk) * EMB + h * NW);
        float z[8];
        qrow(xp, th, z);
        *reinterpret_cast<float4*>(&kv[kl * 4])            = make_float4(z[0], z[1], z[2], z[3]);
        *reinterpret_cast<float4*>(&kv[(KC + kl) * 4])     = make_float4(z[4], z[5], z[6], z[7]);
    }

    // this thread's query; fold 1/sqrt(8)*log2(e) into q so exp2(s) == exp(score)
    const float QS = 0.35355339059327373f * 1.4426950408889634f;
    const int  sq = qc * QC + t;
    float qv[8], oacc[8];
    {
        const float* xp = x + ((size_t)(b * SEQ + sq) * EMB + h * NW);
        float z[8];
        qrow(xp, th, z);
#pragma unroll
        for (int d = 0; d < 8; ++d) { qv[d] = z[d] * QS; oacc[d] = 0.f; }
    }
    float lac = 0.f;

    __syncthreads();

    const float4* kvA = reinterpret_cast<const float4*>(kv);
#pragma unroll 4
    for (int k = 0; k < KC; ++k) {
        float4 ka = kvA[k];          // uniform address -> LDS broadcast
        float4 kb = kvA[KC + k];
        float s = fmaf(qv[0], ka.x, fmaf(qv[1], ka.y, fmaf(qv[2], ka.z, fmaf(qv[3], ka.w,
                  fmaf(qv[4], kb.x, fmaf(qv[5], kb.y, fmaf(qv[6], kb.z, qv[7] * kb.w)))))));
        float p = __builtin_amdgcn_exp2f(s);   // exactly one v_exp_f32
        lac += p;
        oacc[0] = fmaf(p, ka.x, oacc[0]); oacc[1] = fmaf(p, ka.y, oacc[1]);
        oacc[2] = fmaf(p, ka.z, oacc[2]); oacc[3] = fmaf(p, ka.w, oacc[3]);
        oacc[4] = fmaf(p, kb.x, oacc[4]); oacc[5] = fmaf(p, kb.y, oacc[5]);
        oacc[6] = fmaf(p, kb.z, oacc[6]); oacc[7] = fmaf(p, kb.w, oacc[7]);
    }

    // plain coalesced stores of this chunk's partials
    float* op = o_part + (((size_t)kc * 128 + bh) * SEQ + sq) * 8;
    *reinterpret_cast<float4*>(op)     = make_float4(oacc[0], oacc[1], oacc[2], oacc[3]);
    *reinterpret_cast<float4*>(op + 4) = make_float4(oacc[4], oacc[5], oacc[6], oacc[7]);
    l_part[((size_t)kc * 128 + bh) * SEQ + sq] = lac;
}

// Kernel B: out[row, e] = sum_f P[row,f] * W[e,f] + bias[e],
// P[row, h*8+d] = (sum_c o_part[c]) / (sum_c l_part[c]).
// grid = (8192/64 row chunks) x (128/64 col tiles) = 256 blocks, 256 threads.
// 64x64 tile, 4x4 register tile with STRIDED mapping (r = t>>4 + 16*ri,
// c = t&15 + 16*j) so LDS row reads land on distinct banks.
__global__ __launch_bounds__(256, 2) void proj_out(
    const float* __restrict__ o_part,
    const float* __restrict__ l_part,
    const float* __restrict__ W,
    const float* __restrict__ bias,
    float* __restrict__ out)
{
    __shared__ float Pl[64 * PW];             // 33.8 KB
    __shared__ float Wl[64 * PW];             // 33.8 KB
    __shared__ float linv[64 * 16];           // 4 KB
    const int t     = threadIdx.x;
    const int row0  = blockIdx.x * 64;        // global row chunk (same b)
    const int ecol0 = blockIdx.y * 64;        // output column tile
    const int b     = row0 >> 10;
    const int s0    = row0 & 1023;

    // phase 1: 1/l for 64 rows x 16 heads (coalesced: r runs along lanes)
#pragma unroll
    for (int i = 0; i < 4; ++i) {
        const int g = t + 256 * i;            // 1024
        const int h = g >> 6, r = g & 63;
        const size_t a = ((size_t)(b * 16 + h) * SEQ + s0 + r);
        linv[r * 16 + h] = 1.0f / (l_part[a] + l_part[(size_t)128 * SEQ + a]);
    }
    __syncthreads();

    // phase 2a: stage P (sum partials, normalize). Global reads contiguous per head.
#pragma unroll
    for (int i = 0; i < 8; ++i) {
        const int g  = t + 256 * i;           // 2048 float4 groups
        const int h  = g >> 7;                // 0..15
        const int q4 = g & 127;               // 0..127 (64 rows x 2 halves)
        const size_t base = ((size_t)(b * 16 + h) * SEQ + s0) * 8 + q4 * 4;
        float4 v0 = *reinterpret_cast<const float4*>(o_part + base);
        float4 v1 = *reinterpret_cast<const float4*>(o_part + (size_t)128 * SEQ * 8 + base);
        const int r  = q4 >> 1;
        const int d0 = (q4 & 1) * 4;
        const float sc = linv[r * 16 + h];
        float4 v;
        v.x = (v0.x + v1.x) * sc; v.y = (v0.y + v1.y) * sc;
        v.z = (v0.z + v1.z) * sc; v.w = (v0.w + v1.w) * sc;
        *reinterpret_cast<float4*>(&Pl[r * PW + h * 8 + d0]) = v;
    }
    // phase 2b: stage W rows ecol0..ecol0+63 (coalesced)
#pragma unroll
    for (int i = 0; i < 8; ++i) {
        const int g  = t + 256 * i;           // 2048 float4 groups
        const int e  = g >> 5;
        const int k0 = (g & 31) * 4;
        *reinterpret_cast<float4*>(&Wl[e * PW + k0]) =
            *reinterpret_cast<const float4*>(W + (size_t)(ecol0 + e) * EMB + k0);
    }
    __syncthreads();

    // compute: rows rr = (t>>4) + 16*ri, cols cc = (t&15) + 16*j
    const int rb = t >> 4;     // 0..15
    const int cb = t & 15;     // 0..15
    float acc[4][4];
#pragma unroll
    for (int ri = 0; ri < 4; ++ri)
#pragma unroll
        for (int j = 0; j < 4; ++j) acc[ri][j] = 0.f;

    for (int kk = 0; kk < EMB; kk += 4) {
        float4 a[4], w[4];
#pragma unroll
        for (int ri = 0; ri < 4; ++ri)
            a[ri] = *reinterpret_cast<const float4*>(&Pl[(rb + 16 * ri) * PW + kk]);
#pragma unroll
        for (int j = 0; j < 4; ++j)
            w[j] = *reinterpret_cast<const float4*>(&Wl[(cb + 16 * j) * PW + kk]);
#pragma unroll
        for (int ri = 0; ri < 4; ++ri)
#pragma unroll
            for (int j = 0; j < 4; ++j) {
                acc[ri][j] = fmaf(a[ri].x, w[j].x, acc[ri][j]);
                acc[ri][j] = fmaf(a[ri].y, w[j].y, acc[ri][j]);
                acc[ri][j] = fmaf(a[ri].z, w[j].z, acc[ri][j]);
                acc[ri][j] = fmaf(a[ri].w, w[j].w, acc[ri][j]);
            }
    }

    float bv[4];
#pragma unroll
    for (int j = 0; j < 4; ++j) bv[j] = bias[ecol0 + cb + 16 * j];
#pragma unroll
    for (int ri = 0; ri < 4; ++ri) {
        const int row = row0 + rb + 16 * ri;
#pragma unroll
        for (int j = 0; j < 4; ++j)
            out[(size_t)row * EMB + ecol0 + cb + 16 * j] = acc[ri][j] + bv[j];
    }
}

extern "C" void kernel_launch(void* const* d_in, const int* in_sizes, int n_in,
                              void* d_out, int out_size, void* d_ws, size_t ws_size,
                              hipStream_t stream)
{
    const float* x     = (const float*)d_in[0];
    const float* theta = (const float*)d_in[1];
    const float* W     = (const float*)d_in[2];
    const float* bias  = (const float*)d_in[3];
    float* out = (float*)d_out;

    // workspace: o_part = KSPLIT*128*1024*8 fp32 (8 MB), l_part = KSPLIT*128*1024 (1 MB)
    float* o_part = (float*)d_ws;
    float* l_part = (float*)((char*)d_ws + (size_t)KSPLIT * 128 * SEQ * 8 * sizeof(float));

    qattn_partial<<<128 * QSPLIT * KSPLIT, 256, 0, stream>>>(x, theta, o_part, l_part);
    proj_out<<<dim3(BATCH * SEQ / 64, EMB / 64), 256, 0, stream>>>(o_part, l_part, W, bias, out);
}